// Round 3
// baseline (2093.682 us; speedup 1.0000x reference)
//
#include <hip/hip_runtime.h>

// MyRNN: B=128, T=80, E=100, V=10000, U=512
// 8 clusters x 32 member-blocks. Cluster c owns batch rows [16c,16c+16).
// Member m owns output cols [16m,16m+16) of rk0/rk1/k1 (stationary in LDS,
// hi/lo bf16 split). Per step: round A publishes h0 slice, round B publishes
// h1 slice. Cross-block traffic = RELAXED agent-scope atomics only (no
// acquire/release -> no buffer_inv/wbl2; R1 lesson). R2 lesson: per-member
// flag polling (32 lines x 32 lanes x 256 blocks) generated ~37GB of fabric
// reads and queued producer stores behind poll traffic -> ONE monotonic
// counter per cluster, single-lane poll, no-return atomicAdd posts.

typedef __attribute__((ext_vector_type(8))) short short8;
typedef __attribute__((ext_vector_type(4))) float f32x4;

#define MFMA16(a,b,c) __builtin_amdgcn_mfma_f32_16x16x32_bf16(a,b,c,0,0,0)
#define LOAD_RLX(p)    __hip_atomic_load((p), __ATOMIC_RELAXED, __HIP_MEMORY_SCOPE_AGENT)
#define STORE_RLX(p,v) __hip_atomic_store((p), (v), __ATOMIC_RELAXED, __HIP_MEMORY_SCOPE_AGENT)
#define ADD_RLX(p,v)   __hip_atomic_fetch_add((p), (v), __ATOMIC_RELAXED, __HIP_MEMORY_SCOPE_AGENT)

__device__ __forceinline__ short f2bf(float v){
  unsigned u = __float_as_uint(v);
  u = (u + 0x7fffu + ((u >> 16) & 1u)) >> 16;   // RNE to bf16
  return (short)u;
}
__device__ __forceinline__ float bf2f(short s){
  return __uint_as_float(((unsigned)(unsigned short)s) << 16);
}

__launch_bounds__(128, 1)
__global__ void rnn_kernel(const int* __restrict__ tokens,
                           const float* __restrict__ emb,
                           const float* __restrict__ k0,
                           const float* __restrict__ rk0,
                           const float* __restrict__ b0,
                           const float* __restrict__ k1,
                           const float* __restrict__ rk1,
                           const float* __restrict__ b1,
                           const float* __restrict__ wd,
                           const float* __restrict__ bd,
                           float* __restrict__ out,
                           char* __restrict__ ws)
{
  constexpr int T = 80, E = 100, U = 512;
  const int tid  = threadIdx.x;
  const int cl   = blockIdx.x & 7;    // cluster (XCD-aligned heuristic only)
  const int mem  = blockIdx.x >> 3;   // member 0..31
  const int w    = tid >> 6;          // wave id (0/1)
  const int lane = tid & 63;
  const int m    = lane & 15;         // row (A) / col (B,C)
  const int q    = lane >> 4;         // quad 0..3

  __shared__ __align__(16) short sW[6][16][520];   // rk0 hi/lo, rk1 hi/lo, k1 hi/lo : [col][k]
  __shared__ __align__(16) short sH[2][16][520];   // h / h0 staging hi,lo : [row][k]
  __shared__ __align__(16) short sE[2][16][136];   // emb rows hi,lo (K padded to 128 w/ zeros)
  __shared__ __align__(16) short sK0[2][16][136];  // k0 slice hi,lo : [col][k] (padded)
  __shared__ int   sTok[16][80];
  __shared__ float sB0[16], sB1[16];
  __shared__ float sRed[16][8];

  int*      cnts = (int*)ws;                        // 8 counters, 64B apart (memset to 0 by launch)
  unsigned* hPk  = (unsigned*)(ws + 16*1024);       // h1 packed (hi<<16|lo), [128][512]
  unsigned* h0Pk = hPk + 128*U;                     // h0 packed
  int*      cnt  = cnts + cl*16;

  // ---------------- prologue: stationary weights -> LDS ----------------
  const float* mats[3] = { rk0, rk1, k1 };
  for (int mi = 0; mi < 3; ++mi){
    const float* G = mats[mi];
    for (int i = tid; i < 16*U; i += 128){
      int k = i >> 4, c = i & 15;
      float v  = G[k*U + mem*16 + c];
      short hi = f2bf(v);
      short lo = f2bf(v - bf2f(hi));
      sW[2*mi+0][c][k] = hi;
      sW[2*mi+1][c][k] = lo;
    }
  }
  for (int i = tid; i < 2*16*136; i += 128){ ((short*)sE)[i] = 0; ((short*)sK0)[i] = 0; }
  __syncthreads();
  for (int i = tid; i < 16*E; i += 128){
    int e = i >> 4, c = i & 15;
    float v  = k0[e*U + mem*16 + c];
    short hi = f2bf(v);
    short lo = f2bf(v - bf2f(hi));
    sK0[0][c][e] = hi; sK0[1][c][e] = lo;
  }
  for (int i = tid; i < 16*T; i += 128){
    int r = i / T, t = i - r*T;
    sTok[r][t] = tokens[(cl*16 + r)*T + t];
  }
  if (tid < 16){ sB0[tid] = b0[mem*16 + tid]; sB1[tid] = b1[mem*16 + tid]; }
  __syncthreads();

  auto poll = [&](int target){
    if (tid == 0){
      while (LOAD_RLX(cnt) < target) __builtin_amdgcn_s_sleep(1);
    }
    // caller's __syncthreads() provides the compiler/exec barrier
  };
  auto post = [&](){
    // caller's __syncthreads() already drained vmcnt(0) for all waves:
    // slice data is visible at the device-coherent point before the add
    if (tid == 0) ADD_RLX(cnt, 1);
  };
  auto gather = [&](const unsigned* srcPk){
    const unsigned long long* s = (const unsigned long long*)(srcPk + cl*16*U);
    for (int i = tid; i < 4096; i += 128){           // 16 rows x 256 ull
      int row = i >> 8, j = i & 255;
      unsigned long long v = LOAD_RLX(&s[row*256 + j]);
      unsigned p0 = (unsigned)v, p1 = (unsigned)(v >> 32);
      int c = j*2;
      *(unsigned*)&sH[0][row][c] = (p0 >> 16)     | (p1 & 0xffff0000u);
      *(unsigned*)&sH[1][row][c] = (p0 & 0xffffu) | (p1 << 16);
    }
  };

  const f32x4 zero4 = {0.f, 0.f, 0.f, 0.f};

  // ---------------- recurrence ----------------
  for (int t = 0; t < T; ++t){
    // stage emb rows for step t (independent work overlaps the wait)
    for (int i = tid; i < 16*E; i += 128){
      int r = i / E, e = i - r*E;
      float v  = emb[sTok[r][t]*E + e];
      short hi = f2bf(v);
      short lo = f2bf(v - bf2f(hi));
      sE[0][r][e] = hi; sE[1][r][e] = lo;
    }
    if (t > 0) poll(32*2*t);              // all h1(t-1) slices published
    __syncthreads();
    if (t > 0) gather(hPk);
    __syncthreads();

    f32x4 z1a = zero4, z1b = zero4, z1c = zero4, z1d = zero4;   // wave1: h@rk1
    if (w == 0){
      // z0 = x_t@k0 + h@rk0 (4-term hi/lo split = fp32-class)
      f32x4 za = zero4, zb = zero4, zc = zero4, zd = zero4;
      #pragma unroll
      for (int kk = 0; kk < 4; ++kk){
        short8 ah = *(const short8*)&sE[0][m][kk*32 + q*8];
        short8 al = *(const short8*)&sE[1][m][kk*32 + q*8];
        short8 bh = *(const short8*)&sK0[0][m][kk*32 + q*8];
        short8 bl = *(const short8*)&sK0[1][m][kk*32 + q*8];
        za = MFMA16(ah, bh, za); zb = MFMA16(al, bh, zb);
        zc = MFMA16(ah, bl, zc); zd = MFMA16(al, bl, zd);
      }
      if (t > 0){
        #pragma unroll
        for (int kk = 0; kk < 16; ++kk){
          short8 ah = *(const short8*)&sH[0][m][kk*32 + q*8];
          short8 al = *(const short8*)&sH[1][m][kk*32 + q*8];
          short8 bh = *(const short8*)&sW[0][m][kk*32 + q*8];
          short8 bl = *(const short8*)&sW[1][m][kk*32 + q*8];
          za = MFMA16(ah, bh, za); zb = MFMA16(al, bh, zb);
          zc = MFMA16(ah, bl, zc); zd = MFMA16(al, bl, zd);
        }
      }
      f32x4 z = za; z += zb; z += zc; z += zd;
      #pragma unroll
      for (int r = 0; r < 4; ++r){
        float h0v = tanhf(z[r] + sB0[m]);
        short hi = f2bf(h0v);
        short lo = f2bf(h0v - bf2f(hi));
        int gr = cl*16 + q*4 + r, gc = mem*16 + m;
        unsigned pk = ((unsigned)(unsigned short)hi << 16) | (unsigned short)lo;
        STORE_RLX(&h0Pk[gr*U + gc], pk);
      }
    } else {
      if (t > 0){
        #pragma unroll
        for (int kk = 0; kk < 16; ++kk){
          short8 ah = *(const short8*)&sH[0][m][kk*32 + q*8];
          short8 al = *(const short8*)&sH[1][m][kk*32 + q*8];
          short8 bh = *(const short8*)&sW[2][m][kk*32 + q*8];
          short8 bl = *(const short8*)&sW[3][m][kk*32 + q*8];
          z1a = MFMA16(ah, bh, z1a); z1b = MFMA16(al, bh, z1b);
          z1c = MFMA16(ah, bl, z1c); z1d = MFMA16(al, bl, z1d);
        }
      }
    }
    __syncthreads();                      // drains vmcnt(0): h0 stores at MALL
    post();                               // counter -> 32*(2t+1) when all members in

    // ---- round B: h1 = tanh(h0@k1 + h@rk1 + b1)
    poll(32*(2*t + 1));
    __syncthreads();
    gather(h0Pk);
    __syncthreads();
    if (w == 1){
      f32x4 za = zero4, zb = zero4, zc = zero4, zd = zero4;
      #pragma unroll
      for (int kk = 0; kk < 16; ++kk){
        short8 ah = *(const short8*)&sH[0][m][kk*32 + q*8];
        short8 al = *(const short8*)&sH[1][m][kk*32 + q*8];
        short8 bh = *(const short8*)&sW[4][m][kk*32 + q*8];
        short8 bl = *(const short8*)&sW[5][m][kk*32 + q*8];
        za = MFMA16(ah, bh, za); zb = MFMA16(al, bh, zb);
        zc = MFMA16(ah, bl, zc); zd = MFMA16(al, bl, zd);
      }
      f32x4 z = za; z += zb; z += zc; z += zd;
      z += z1a; z += z1b; z += z1c; z += z1d;
      #pragma unroll
      for (int r = 0; r < 4; ++r){
        float h1v = tanhf(z[r] + sB1[m]);
        short hi = f2bf(h1v);
        short lo = f2bf(h1v - bf2f(hi));
        int gr = cl*16 + q*4 + r, gc = mem*16 + m;
        unsigned pk = ((unsigned)(unsigned short)hi << 16) | (unsigned short)lo;
        STORE_RLX(&hPk[gr*U + gc], pk);
      }
    }
    __syncthreads();                      // drains vmcnt(0): h1 stores at MALL
    post();                               // counter -> 32*(2t+2)
  }

  // ---------------- epilogue: logits = h@wd + bd ; sigmoid ----------------
  if (mem == 0){
    poll(32*2*T);
    __syncthreads();
    gather(hPk);
    __syncthreads();
    {
      int row = tid >> 3, seg = tid & 7;
      float acc = 0.f;
      for (int u = seg*64; u < seg*64 + 64; ++u){
        float hv = bf2f(sH[0][row][u]) + bf2f(sH[1][row][u]);
        acc += hv * wd[u];
      }
      sRed[row][seg] = acc;
    }
    __syncthreads();
    if (tid < 16){
      float s = bd[0];
      #pragma unroll
      for (int j = 0; j < 8; ++j) s += sRed[tid][j];
      out[cl*16 + tid] = 1.f / (1.f + expf(-s));
    }
  }
}

extern "C" void kernel_launch(void* const* d_in, const int* in_sizes, int n_in,
                              void* d_out, int out_size, void* d_ws, size_t ws_size,
                              hipStream_t stream) {
  const int*   tokens = (const int*)  d_in[0];
  const float* emb    = (const float*)d_in[1];
  const float* k0     = (const float*)d_in[2];
  const float* rk0    = (const float*)d_in[3];
  const float* b0     = (const float*)d_in[4];
  const float* k1     = (const float*)d_in[5];
  const float* rk1    = (const float*)d_in[6];
  const float* b1     = (const float*)d_in[7];
  const float* wd     = (const float*)d_in[8];
  const float* bd     = (const float*)d_in[9];

  // Zero the sync counters (0xAA poison breaks monotonic +1 arithmetic).
  // hipMemsetAsync on the capture stream is graph-capture legal.
  hipMemsetAsync(d_ws, 0, 4096, stream);

  hipLaunchKernelGGL(rnn_kernel, dim3(256), dim3(128), 0, stream,
                     tokens, emb, k0, rk0, b0, k1, rk1, b1, wd, bd,
                     (float*)d_out, (char*)d_ws);
}

// Round 4
// 921.519 us; speedup vs baseline: 2.2720x; 2.2720x over previous
//
#include <hip/hip_runtime.h>

// MyRNN: B=128, T=80, E=100, V=10000, U=512
// 8 clusters x 32 member-blocks. Cluster c owns batch rows [16c,16c+16).
// Member m owns output cols [16m,16m+16) of rk0/rk1/k1 (stationary in LDS,
// hi/lo bf16 split). Per step: round A publishes h0 slice, round B publishes
// h1 slice. Cross-block traffic = RELAXED agent-scope atomics only.
// R1 lesson: acquire/release -> buffer_inv/wbl2 L2 thrash (24us/round).
// R2/R3 lesson: round time pinned at 13us regardless of poll scheme ->
// serializer is the gather loop: one 8B atomic load in flight per thread
// (32 serial far-latencies). R4 fix: BATCH 16 loads into regs, then unpack.

typedef __attribute__((ext_vector_type(8))) short short8;
typedef __attribute__((ext_vector_type(4))) float f32x4;

#define MFMA16(a,b,c) __builtin_amdgcn_mfma_f32_16x16x32_bf16(a,b,c,0,0,0)
#define LOAD_RLX(p)    __hip_atomic_load((p), __ATOMIC_RELAXED, __HIP_MEMORY_SCOPE_AGENT)
#define STORE_RLX(p,v) __hip_atomic_store((p), (v), __ATOMIC_RELAXED, __HIP_MEMORY_SCOPE_AGENT)
#define ADD_RLX(p,v)   __hip_atomic_fetch_add((p), (v), __ATOMIC_RELAXED, __HIP_MEMORY_SCOPE_AGENT)

__device__ __forceinline__ short f2bf(float v){
  unsigned u = __float_as_uint(v);
  u = (u + 0x7fffu + ((u >> 16) & 1u)) >> 16;   // RNE to bf16
  return (short)u;
}
__device__ __forceinline__ float bf2f(short s){
  return __uint_as_float(((unsigned)(unsigned short)s) << 16);
}
__device__ __forceinline__ float fast_tanh(float x){
  // tanh(x) = (e^{2x}-1)/(e^{2x}+1); clamp keeps e finite (tanh(+-15)==+-1 in fp32)
  x = fminf(15.f, fmaxf(-15.f, x));
  float e = __expf(2.f * x);
  return (e - 1.f) * __builtin_amdgcn_rcpf(e + 1.f);
}

__launch_bounds__(128, 1)
__global__ void rnn_kernel(const int* __restrict__ tokens,
                           const float* __restrict__ emb,
                           const float* __restrict__ k0,
                           const float* __restrict__ rk0,
                           const float* __restrict__ b0,
                           const float* __restrict__ k1,
                           const float* __restrict__ rk1,
                           const float* __restrict__ b1,
                           const float* __restrict__ wd,
                           const float* __restrict__ bd,
                           float* __restrict__ out,
                           char* __restrict__ ws)
{
  constexpr int T = 80, E = 100, U = 512;
  const int tid  = threadIdx.x;
  const int cl   = blockIdx.x & 7;    // cluster (XCD-aligned heuristic only)
  const int mem  = blockIdx.x >> 3;   // member 0..31
  const int w    = tid >> 6;          // wave id (0/1)
  const int lane = tid & 63;
  const int m    = lane & 15;         // row (A) / col (B,C)
  const int q    = lane >> 4;         // quad 0..3

  __shared__ __align__(16) short sW[6][16][520];   // rk0 hi/lo, rk1 hi/lo, k1 hi/lo : [col][k]
  __shared__ __align__(16) short sH[2][16][520];   // h / h0 staging hi,lo : [row][k]
  __shared__ __align__(16) short sE[2][16][136];   // emb rows hi,lo (K padded to 128 w/ zeros)
  __shared__ __align__(16) short sK0[2][16][136];  // k0 slice hi,lo : [col][k] (padded)
  __shared__ int   sTok[16][80];
  __shared__ float sB0[16], sB1[16];
  __shared__ float sRed[16][8];

  int*      cnts = (int*)ws;                        // 8 counters, 64B apart (memset to 0 by launch)
  unsigned* hPk  = (unsigned*)(ws + 16*1024);       // h1 packed (hi<<16|lo), [128][512]
  unsigned* h0Pk = hPk + 128*U;                     // h0 packed
  int*      cnt  = cnts + cl*16;

  // ---------------- prologue: stationary weights -> LDS ----------------
  const float* mats[3] = { rk0, rk1, k1 };
  for (int mi = 0; mi < 3; ++mi){
    const float* G = mats[mi];
    for (int i = tid; i < 16*U; i += 128){
      int k = i >> 4, c = i & 15;
      float v  = G[k*U + mem*16 + c];
      short hi = f2bf(v);
      short lo = f2bf(v - bf2f(hi));
      sW[2*mi+0][c][k] = hi;
      sW[2*mi+1][c][k] = lo;
    }
  }
  for (int i = tid; i < 2*16*136; i += 128){ ((short*)sE)[i] = 0; ((short*)sK0)[i] = 0; }
  __syncthreads();
  for (int i = tid; i < 16*E; i += 128){
    int e = i >> 4, c = i & 15;
    float v  = k0[e*U + mem*16 + c];
    short hi = f2bf(v);
    short lo = f2bf(v - bf2f(hi));
    sK0[0][c][e] = hi; sK0[1][c][e] = lo;
  }
  for (int i = tid; i < 16*T; i += 128){
    int r = i / T, t = i - r*T;
    sTok[r][t] = tokens[(cl*16 + r)*T + t];
  }
  if (tid < 16){ sB0[tid] = b0[mem*16 + tid]; sB1[tid] = b1[mem*16 + tid]; }
  __syncthreads();

  auto poll = [&](int target){
    if (tid == 0){
      while (LOAD_RLX(cnt) < target) __builtin_amdgcn_s_sleep(1);
    }
    // caller's __syncthreads() provides the compiler/exec barrier
  };
  auto post = [&](){
    // caller's __syncthreads() already drained vmcnt(0) for all waves:
    // slice data is visible at the device-coherent point before the add
    if (tid == 0) ADD_RLX(cnt, 1);
  };
  // Batched gather: 16 far-loads in flight per thread, then unpack.
  auto gather = [&](const unsigned* srcPk){
    const unsigned long long* s = (const unsigned long long*)(srcPk + cl*16*U);
    #pragma unroll
    for (int half = 0; half < 2; ++half){
      unsigned long long r[16];
      #pragma unroll
      for (int j = 0; j < 16; ++j)
        r[j] = LOAD_RLX(&s[half*2048 + j*128 + tid]);
      #pragma unroll
      for (int j = 0; j < 16; ++j){
        int i = half*2048 + j*128 + tid;
        int row = i >> 8, c = (i & 255) * 2;
        unsigned p0 = (unsigned)r[j], p1 = (unsigned)(r[j] >> 32);
        *(unsigned*)&sH[0][row][c] = (p0 >> 16)     | (p1 & 0xffff0000u);
        *(unsigned*)&sH[1][row][c] = (p0 & 0xffffu) | (p1 << 16);
      }
    }
  };

  const f32x4 zero4 = {0.f, 0.f, 0.f, 0.f};

  // ---------------- recurrence ----------------
  for (int t = 0; t < T; ++t){
    // stage emb rows for step t (independent work overlaps the wait)
    for (int i = tid; i < 16*E; i += 128){
      int r = i / E, e = i - r*E;
      float v  = emb[sTok[r][t]*E + e];
      short hi = f2bf(v);
      short lo = f2bf(v - bf2f(hi));
      sE[0][r][e] = hi; sE[1][r][e] = lo;
    }
    if (t > 0) poll(32*2*t);              // all h1(t-1) slices published
    __syncthreads();
    if (t > 0) gather(hPk);
    __syncthreads();

    f32x4 z1a = zero4, z1b = zero4, z1c = zero4, z1d = zero4;   // wave1: h@rk1
    if (w == 0){
      // z0 = x_t@k0 + h@rk0 (4-term hi/lo split = fp32-class)
      f32x4 za = zero4, zb = zero4, zc = zero4, zd = zero4;
      #pragma unroll
      for (int kk = 0; kk < 4; ++kk){
        short8 ah = *(const short8*)&sE[0][m][kk*32 + q*8];
        short8 al = *(const short8*)&sE[1][m][kk*32 + q*8];
        short8 bh = *(const short8*)&sK0[0][m][kk*32 + q*8];
        short8 bl = *(const short8*)&sK0[1][m][kk*32 + q*8];
        za = MFMA16(ah, bh, za); zb = MFMA16(al, bh, zb);
        zc = MFMA16(ah, bl, zc); zd = MFMA16(al, bl, zd);
      }
      if (t > 0){
        #pragma unroll
        for (int kk = 0; kk < 16; ++kk){
          short8 ah = *(const short8*)&sH[0][m][kk*32 + q*8];
          short8 al = *(const short8*)&sH[1][m][kk*32 + q*8];
          short8 bh = *(const short8*)&sW[0][m][kk*32 + q*8];
          short8 bl = *(const short8*)&sW[1][m][kk*32 + q*8];
          za = MFMA16(ah, bh, za); zb = MFMA16(al, bh, zb);
          zc = MFMA16(ah, bl, zc); zd = MFMA16(al, bl, zd);
        }
      }
      f32x4 z = za; z += zb; z += zc; z += zd;
      #pragma unroll
      for (int r = 0; r < 4; ++r){
        float h0v = fast_tanh(z[r] + sB0[m]);
        short hi = f2bf(h0v);
        short lo = f2bf(h0v - bf2f(hi));
        int gr = cl*16 + q*4 + r, gc = mem*16 + m;
        unsigned pk = ((unsigned)(unsigned short)hi << 16) | (unsigned short)lo;
        STORE_RLX(&h0Pk[gr*U + gc], pk);
      }
    } else {
      if (t > 0){
        #pragma unroll
        for (int kk = 0; kk < 16; ++kk){
          short8 ah = *(const short8*)&sH[0][m][kk*32 + q*8];
          short8 al = *(const short8*)&sH[1][m][kk*32 + q*8];
          short8 bh = *(const short8*)&sW[2][m][kk*32 + q*8];
          short8 bl = *(const short8*)&sW[3][m][kk*32 + q*8];
          z1a = MFMA16(ah, bh, z1a); z1b = MFMA16(al, bh, z1b);
          z1c = MFMA16(ah, bl, z1c); z1d = MFMA16(al, bl, z1d);
        }
      }
    }
    __syncthreads();                      // drains vmcnt(0): h0 stores at coherent point
    post();                               // counter -> 32*(2t+1) when all members in

    // ---- round B: h1 = tanh(h0@k1 + h@rk1 + b1)
    poll(32*(2*t + 1));
    __syncthreads();
    gather(h0Pk);
    __syncthreads();
    if (w == 1){
      f32x4 za = zero4, zb = zero4, zc = zero4, zd = zero4;
      #pragma unroll
      for (int kk = 0; kk < 16; ++kk){
        short8 ah = *(const short8*)&sH[0][m][kk*32 + q*8];
        short8 al = *(const short8*)&sH[1][m][kk*32 + q*8];
        short8 bh = *(const short8*)&sW[4][m][kk*32 + q*8];
        short8 bl = *(const short8*)&sW[5][m][kk*32 + q*8];
        za = MFMA16(ah, bh, za); zb = MFMA16(al, bh, zb);
        zc = MFMA16(ah, bl, zc); zd = MFMA16(al, bl, zd);
      }
      f32x4 z = za; z += zb; z += zc; z += zd;
      z += z1a; z += z1b; z += z1c; z += z1d;
      #pragma unroll
      for (int r = 0; r < 4; ++r){
        float h1v = fast_tanh(z[r] + sB1[m]);
        short hi = f2bf(h1v);
        short lo = f2bf(h1v - bf2f(hi));
        int gr = cl*16 + q*4 + r, gc = mem*16 + m;
        unsigned pk = ((unsigned)(unsigned short)hi << 16) | (unsigned short)lo;
        STORE_RLX(&hPk[gr*U + gc], pk);
      }
    }
    __syncthreads();                      // drains vmcnt(0): h1 stores at coherent point
    post();                               // counter -> 32*(2t+2)
  }

  // ---------------- epilogue: logits = h@wd + bd ; sigmoid ----------------
  if (mem == 0){
    poll(32*2*T);
    __syncthreads();
    gather(hPk);
    __syncthreads();
    {
      int row = tid >> 3, seg = tid & 7;
      float acc = 0.f;
      for (int u = seg*64; u < seg*64 + 64; ++u){
        float hv = bf2f(sH[0][row][u]) + bf2f(sH[1][row][u]);
        acc += hv * wd[u];
      }
      sRed[row][seg] = acc;
    }
    __syncthreads();
    if (tid < 16){
      float s = bd[0];
      #pragma unroll
      for (int j = 0; j < 8; ++j) s += sRed[tid][j];
      out[cl*16 + tid] = 1.f / (1.f + __expf(-s));
    }
  }
}

extern "C" void kernel_launch(void* const* d_in, const int* in_sizes, int n_in,
                              void* d_out, int out_size, void* d_ws, size_t ws_size,
                              hipStream_t stream) {
  const int*   tokens = (const int*)  d_in[0];
  const float* emb    = (const float*)d_in[1];
  const float* k0     = (const float*)d_in[2];
  const float* rk0    = (const float*)d_in[3];
  const float* b0     = (const float*)d_in[4];
  const float* k1     = (const float*)d_in[5];
  const float* rk1    = (const float*)d_in[6];
  const float* b1     = (const float*)d_in[7];
  const float* wd     = (const float*)d_in[8];
  const float* bd     = (const float*)d_in[9];

  // Zero the sync counters (0xAA poison breaks monotonic +1 arithmetic).
  hipMemsetAsync(d_ws, 0, 4096, stream);

  hipLaunchKernelGGL(rnn_kernel, dim3(256), dim3(128), 0, stream,
                     tokens, emb, k0, rk0, b0, k1, rk1, b1, wd, bd,
                     (float*)d_out, (char*)d_ws);
}